// Round 5
// baseline (413.639 us; speedup 1.0000x reference)
//
#include <hip/hip_runtime.h>

// ============================================================================
// MixerBlock (attention QK^T/softmax is dead code; heads = V only):
//   x1 = LN1(patches); sa = x1 @ Wc^T + bc  (Wc = out_w @ Wv, precomputed)
//   x2 = sa + x1 (fp32, in d_out); x3 = LN2(x2)
//   h = selu(x3 @ w1^T + b1); out = h @ w2^T + b2 + x3
// R5 change vs R4: 3-stage LDS ring + fine-grained s_waitcnt vmcnt(6) + raw
// s_barrier (AITER pattern). Prefetch distance 2 iters; the barrier no longer
// drains the just-issued loads (R2-R4 limiter: exposed latency at vmcnt(0)).
// Requires K/32 % 3 == 0 (holds: K=768 -> 24, K=3072 -> 96).
// Kept: 128x256 block tile, 128x64 wave tile, 16x16x32 MFMA, chunk swizzle
// (0 bank conflicts), XCD m-band remap (FETCH at floor).
// ============================================================================

typedef __bf16 bf16;
typedef __bf16 bf16x8 __attribute__((ext_vector_type(8)));
typedef __bf16 bf16x4 __attribute__((ext_vector_type(4)));
typedef float  f32x4  __attribute__((ext_vector_type(4)));

#define N_ROWS  16384   // B*S = 8*2048

#define AS1(p) ((const __attribute__((address_space(1))) void*)(p))
#define AS3(p) ((__attribute__((address_space(3))) void*)(p))

// s_waitcnt imm (gfx9 encoding): vmcnt[3:0]|[15:14], expcnt[6:4], lgkmcnt[11:8]
// leave expcnt/lgkmcnt unconstrained (compiler handles ds_read deps itself)
#define WAIT_VM6 0x0F76   // vmcnt(6): newest 6 loads may stay in flight
#define WAIT_VM0 0x0F70   // vmcnt(0): full drain (final iter only)

// ---------------------------------------------------------------------------
__global__ __launch_bounds__(256) void cast_kernel(const float* __restrict__ x,
                                                   bf16* __restrict__ y, int n4) {
  int i = blockIdx.x * 256 + threadIdx.x;
  if (i >= n4) return;
  float4 v = ((const float4*)x)[i];
  bf16x4 o = {(bf16)v.x, (bf16)v.y, (bf16)v.z, (bf16)v.w};
  *(bf16x4*)(y + 4 * (size_t)i) = o;
}

// ---------------------------------------------------------------------------
// WvT[k][j] = in_weight[(j*3+2)*768 + k]
__global__ __launch_bounds__(256) void wvt_kernel(const float* __restrict__ in_weight,
                                                  bf16* __restrict__ wvt) {
  int k = blockIdx.x * 256 + threadIdx.x;
  int j = blockIdx.y;
  wvt[(size_t)k * 768 + j] = (bf16)in_weight[((size_t)j * 3 + 2) * 768 + k];
}

// ---------------------------------------------------------------------------
__global__ __launch_bounds__(64) void bias_combine_kernel(const float* __restrict__ out_w,
                                                          const float* __restrict__ in_bias,
                                                          const float* __restrict__ out_b,
                                                          float* __restrict__ bc) {
  int n = blockIdx.x, l = threadIdx.x;
  float s = 0.f;
  for (int j = l; j < 768; j += 64) s += out_w[(size_t)n * 768 + j] * in_bias[j * 3 + 2];
#pragma unroll
  for (int off = 32; off > 0; off >>= 1) s += __shfl_xor(s, off, 64);
  if (l == 0) bc[n] = s + out_b[n];
}

// ---------------------------------------------------------------------------
__global__ __launch_bounds__(256) void ln_kernel(const float* __restrict__ x,
                                                 const float* __restrict__ g,
                                                 const float* __restrict__ b,
                                                 bf16* __restrict__ y) {
  const int row = blockIdx.x;
  const float* xr = x + (size_t)row * 768;
  float v[3], s1 = 0.f, s2 = 0.f;
#pragma unroll
  for (int i = 0; i < 3; ++i) {
    v[i] = xr[threadIdx.x + i * 256];
    s1 += v[i];
    s2 += v[i] * v[i];
  }
#pragma unroll
  for (int off = 32; off > 0; off >>= 1) {
    s1 += __shfl_xor(s1, off, 64);
    s2 += __shfl_xor(s2, off, 64);
  }
  __shared__ float red[8];
  int w = threadIdx.x >> 6, l = threadIdx.x & 63;
  if (l == 0) { red[w * 2] = s1; red[w * 2 + 1] = s2; }
  __syncthreads();
  s1 = red[0] + red[2] + red[4] + red[6];
  s2 = red[1] + red[3] + red[5] + red[7];
  const float mu = s1 * (1.f / 768.f);
  const float var = s2 * (1.f / 768.f) - mu * mu;
  const float rstd = rsqrtf(var + 1e-5f);
#pragma unroll
  for (int i = 0; i < 3; ++i) {
    int d = threadIdx.x + i * 256;
    y[(size_t)row * 768 + d] = (bf16)((v[i] - mu) * rstd * g[d] + b[d]);
  }
}

// ---------------------------------------------------------------------------
// One pipelined K-step. SLOT/WIMM compile-time; ds_read ring base folds into
// the 16-bit instruction offset. Order: wait(stage SLOT ready) -> barrier ->
// issue stage SLOT+2 (overwrites SLOT-1, already consumed by all waves) ->
// compute stage SLOT.
#define SLOT_ELEMS (384 * 32)   // (128 A-rows + 256 B-rows) * 32 k * bf16

template <int SLOT, int WIMM>
__device__ __forceinline__ void kstep(bf16* __restrict__ ring,
                                      const bf16* const (&gA)[2],
                                      const bf16* const (&gB)[4],
                                      const int (&ldA)[2], const int (&ldB)[4],
                                      const int (&offA)[8], const int (&offB)[4],
                                      f32x4 (&acc)[8][4], long& k_next,
                                      bool doIssue) {
  __builtin_amdgcn_s_waitcnt(WIMM);
  __builtin_amdgcn_s_barrier();
  if (doIssue) {
    bf16* da = ring + ((SLOT + 2) % 3) * SLOT_ELEMS;
    bf16* db = da + 128 * 32;
#pragma unroll
    for (int i = 0; i < 2; ++i)
      __builtin_amdgcn_global_load_lds(AS1(gA[i] + k_next), AS3(&da[ldA[i]]), 16, 0, 0);
#pragma unroll
    for (int j = 0; j < 4; ++j)
      __builtin_amdgcn_global_load_lds(AS1(gB[j] + k_next), AS3(&db[ldB[j]]), 16, 0, 0);
    k_next += 32;
  }
  const bf16* ca = ring + SLOT * SLOT_ELEMS;
  const bf16* cb = ca + 128 * 32;
  bf16x8 bfr[4];
#pragma unroll
  for (int ni = 0; ni < 4; ++ni) bfr[ni] = *(const bf16x8*)&cb[offB[ni]];
#pragma unroll
  for (int mi = 0; mi < 8; ++mi) {
    const bf16x8 af = *(const bf16x8*)&ca[offA[mi]];
#pragma unroll
    for (int ni = 0; ni < 4; ++ni)
      acc[mi][ni] = __builtin_amdgcn_mfma_f32_16x16x32_bf16(af, bfr[ni],
                                                            acc[mi][ni], 0, 0, 0);
  }
}

// ---------------------------------------------------------------------------
// C[M][N] = A[M][K] @ B[N][K]^T (+ epilogue). Block tile 128x256, BK=32,
// 4 waves each owning 128x64. 3-stage LDS ring, vmcnt(6) pipeline.
// EPI 0: bf16 = acc | EPI 1: f32 = acc + bias[n] + resid | EPI 2: bf16 = selu
template <int EPI>
__global__ __launch_bounds__(256, 2) void gemm_bt(const bf16* __restrict__ A,
                                                  const bf16* __restrict__ B,
                                                  const float* __restrict__ bias,
                                                  const bf16* __restrict__ resid,
                                                  void* __restrict__ out,
                                                  int M, int N, int K) {
  __shared__ bf16 ring[3 * SLOT_ELEMS];   // 72 KB
  const int tid = threadIdx.x;
  const int w = tid >> 6, l = tid & 63;
  const int q = l >> 4, m16 = l & 15;

  // XCD-aware remap (XCD = linear%8): each XCD owns a contiguous band of
  // gridy/8 m-strips, m fastest -> A band L2-resident across n-tiles.
  int mtile, ntile;
  {
    const int L = blockIdx.y * gridDim.x + blockIdx.x;
    const int gy = gridDim.y;
    if ((gy & 7) == 0) {
      const int mpx = gy >> 3;
      const int xcd = L & 7;
      const int slot = L >> 3;
      mtile = xcd * mpx + (slot % mpx);
      ntile = slot / mpx;
    } else {
      mtile = blockIdx.y; ntile = blockIdx.x;
    }
  }
  const long tileM = (long)mtile * 128;
  const long tileN = (long)ntile * 256;

  // staging geometry (chunk swizzle: stored col (ch&3) holds logical col
  // ((ch&3)-(row>>1))&3 -> frag ds_read_b128 conflict-free)
  const bf16* gA[2]; int ldA[2];
#pragma unroll
  for (int i = 0; i < 2; ++i) {
    const int ch = tid + i * 256;
    const int row = ch >> 2;
    const int cl = ((ch & 3) - (row >> 1)) & 3;
    gA[i] = A + (tileM + row) * (long)K + cl * 8;
    ldA[i] = ch * 8;
  }
  const bf16* gB[4]; int ldB[4];
#pragma unroll
  for (int j = 0; j < 4; ++j) {
    const int ch = tid + j * 256;
    const int row = ch >> 2;
    const int cl = ((ch & 3) - (row >> 1)) & 3;
    gB[j] = B + (tileN + row) * (long)K + cl * 8;
    ldB[j] = ch * 8;
  }

  // fragment LDS offsets (logical (r,q) lives at r*32 + ((q+(r>>1))&3)*8)
  int offA[8], offB[4];
#pragma unroll
  for (int mi = 0; mi < 8; ++mi) {
    const int r = mi * 16 + m16;
    offA[mi] = r * 32 + (((q + (r >> 1)) & 3) << 3);
  }
#pragma unroll
  for (int ni = 0; ni < 4; ++ni) {
    const int r = w * 64 + ni * 16 + m16;
    offB[ni] = r * 32 + (((q + (r >> 1)) & 3) << 3);
  }

  f32x4 acc[8][4] = {};

  // prologue: stage slots 0 and 1 (k=0, k=32)
#pragma unroll
  for (int s = 0; s < 2; ++s) {
    bf16* da = ring + s * SLOT_ELEMS;
    bf16* db = da + 128 * 32;
#pragma unroll
    for (int i = 0; i < 2; ++i)
      __builtin_amdgcn_global_load_lds(AS1(gA[i] + s * 32), AS3(&da[ldA[i]]), 16, 0, 0);
#pragma unroll
    for (int j = 0; j < 4; ++j)
      __builtin_amdgcn_global_load_lds(AS1(gB[j] + s * 32), AS3(&db[ldB[j]]), 16, 0, 0);
  }
  long k_next = 64;

  const int T = K >> 5;   // #K-iters; caller guarantees T % 3 == 0, T >= 6
#pragma unroll 1
  for (int g = 0; g < T - 3; g += 3) {
    kstep<0, WAIT_VM6>(ring, gA, gB, ldA, ldB, offA, offB, acc, k_next, true);
    kstep<1, WAIT_VM6>(ring, gA, gB, ldA, ldB, offA, offB, acc, k_next, true);
    kstep<2, WAIT_VM6>(ring, gA, gB, ldA, ldB, offA, offB, acc, k_next, true);
  }
  // final group: last issue happens at i = T-3 (stage T-1)
  kstep<0, WAIT_VM6>(ring, gA, gB, ldA, ldB, offA, offB, acc, k_next, true);
  kstep<1, WAIT_VM6>(ring, gA, gB, ldA, ldB, offA, offB, acc, k_next, false);
  kstep<2, WAIT_VM0>(ring, gA, gB, ldA, ldB, offA, offB, acc, k_next, false);

  // epilogue: C/D layout col = lane&15, row = (lane>>4)*4 + reg (m89-verified)
  const long colBase = tileN + (long)w * 64 + m16;
  const long rowBase = tileM + q * 4;
#pragma unroll
  for (int mi = 0; mi < 8; ++mi) {
#pragma unroll
    for (int r = 0; r < 4; ++r) {
      const long row = rowBase + mi * 16 + r;
#pragma unroll
      for (int ni = 0; ni < 4; ++ni) {
        const long col = colBase + ni * 16;
        float v = acc[mi][ni][r];
        if (EPI == 0) {
          ((bf16*)out)[row * N + col] = (bf16)v;
        } else if (EPI == 1) {
          v += bias[col] + (float)resid[row * N + col];
          ((float*)out)[row * N + col] = v;
        } else {
          v += bias[col];
          v = v > 0.f ? 1.0507009873554805f * v
                      : 1.0507009873554805f * 1.6732632423543772f * (__expf(v) - 1.f);
          ((bf16*)out)[row * N + col] = (bf16)v;
        }
      }
    }
  }
}

// ---------------------------------------------------------------------------
extern "C" void kernel_launch(void* const* d_in, const int* in_sizes, int n_in,
                              void* d_out, int out_size, void* d_ws, size_t ws_size,
                              hipStream_t stream) {
  const float* patches   = (const float*)d_in[0];
  const float* in_weight = (const float*)d_in[1];
  const float* in_bias   = (const float*)d_in[2];
  const float* out_w     = (const float*)d_in[3];
  const float* out_b     = (const float*)d_in[4];
  const float* mlp_w1    = (const float*)d_in[5];
  const float* mlp_b1    = (const float*)d_in[6];
  const float* mlp_w2    = (const float*)d_in[7];
  const float* mlp_b2    = (const float*)d_in[8];
  const float* ln1_g     = (const float*)d_in[9];
  const float* ln1_b     = (const float*)d_in[10];
  const float* ln2_g     = (const float*)d_in[11];
  const float* ln2_b     = (const float*)d_in[12];

  char* ws = (char*)d_ws;
  const size_t MB = 1024 * 1024;
  bf16* Wc   = (bf16*)(ws + 0);
  bf16* w1b  = (bf16*)(ws + 2 * MB);
  bf16* w2b  = (bf16*)(ws + 8 * MB);
  bf16* owb  = (bf16*)(ws + 14 * MB);
  bf16* wvt  = (bf16*)(ws + 16 * MB);
  float* bc  = (float*)(ws + 18 * MB);
  bf16* X1   = (bf16*)(ws + 20 * MB);  // reused as X3
  bf16* X3   = (bf16*)(ws + 20 * MB);
  bf16* H    = (bf16*)(ws + 48 * MB);
  float* X2  = (float*)d_out;          // fp32 scratch inside d_out

  cast_kernel<<<(3072 * 768 / 4 + 255) / 256, 256, 0, stream>>>(mlp_w1, w1b, 3072 * 768 / 4);
  cast_kernel<<<(768 * 3072 / 4 + 255) / 256, 256, 0, stream>>>(mlp_w2, w2b, 768 * 3072 / 4);
  cast_kernel<<<(768 * 768 / 4 + 255) / 256, 256, 0, stream>>>(out_w, owb, 768 * 768 / 4);
  wvt_kernel<<<dim3(3, 768), 256, 0, stream>>>(in_weight, wvt);
  bias_combine_kernel<<<768, 64, 0, stream>>>(out_w, in_bias, out_b, bc);
  gemm_bt<0><<<dim3(3, 6), 256, 0, stream>>>(owb, wvt, nullptr, nullptr, Wc, 768, 768, 768);

  ln_kernel<<<N_ROWS, 256, 0, stream>>>(patches, ln1_g, ln1_b, X1);
  gemm_bt<1><<<dim3(3, 128), 256, 0, stream>>>(X1, Wc, bc, X1, X2, N_ROWS, 768, 768);
  ln_kernel<<<N_ROWS, 256, 0, stream>>>(X2, ln2_g, ln2_b, X3);
  gemm_bt<2><<<dim3(12, 128), 256, 0, stream>>>(X3, w1b, mlp_b1, nullptr, H, N_ROWS, 3072, 768);
  gemm_bt<1><<<dim3(3, 128), 256, 0, stream>>>(H, w2b, mlp_b2, X3, d_out, N_ROWS, 768, 3072);
}

// Round 6
// 407.559 us; speedup vs baseline: 1.0149x; 1.0149x over previous
//
#include <hip/hip_runtime.h>

// ============================================================================
// MixerBlock (attention QK^T/softmax is dead code; heads = V only):
//   x1 = LN1(patches); sa = x1 @ Wc^T + bc  (Wc = out_w @ Wv, precomputed)
//   x2 = sa + x1 (bf16, ws); x3 = LN2(x2)
//   h = selu(x3 @ w1^T + b1); out = h @ w2^T + b2 + x3
// R6 changes vs R5:
//   - gemm: 512 threads = 8 waves (2x4), wave tile 64x64, ONE shared ring ->
//     2 waves/SIMD interleave (R5 had 1 wave/SIMD: ds_read latency + wait
//     tails exposed, MfmaUtil capped at 31%).
//   - 4-stage ring (96 KB), prefetch distance 3 iters, tail waits VM6/VM3/VM0.
//   - wvt: LDS-tiled coalesced transpose (was scattered 2B writes).
//   - X2 bf16 in ws (saves ~50 MB traffic); casts merged into one kernel.
// Kept: 16x16x32 MFMA, chunk swizzle (0 bank conflicts), XCD m-band remap.
// ============================================================================

typedef __bf16 bf16;
typedef __bf16 bf16x8 __attribute__((ext_vector_type(8)));
typedef __bf16 bf16x4 __attribute__((ext_vector_type(4)));
typedef float  f32x4  __attribute__((ext_vector_type(4)));

#define N_ROWS  16384   // B*S = 8*2048

#define AS1(p) ((const __attribute__((address_space(1))) void*)(p))
#define AS3(p) ((__attribute__((address_space(3))) void*)(p))

// s_waitcnt imm (gfx9): vmcnt[3:0]|[15:14], expcnt[6:4]=7, lgkmcnt[11:8]=0xF
#define VM6 0x0F76
#define VM3 0x0F73
#define VM0 0x0F70

// ---------------------------------------------------------------------------
// merged fp32->bf16 casts: mlp_w1 | mlp_w2 | out_w (4 elems/thread)
#define N1 589824   // 3072*768/4
#define N2 589824   // 768*3072/4
#define N3 147456   // 768*768/4
__global__ __launch_bounds__(256) void prep_cast(const float* __restrict__ w1,
                                                 const float* __restrict__ w2,
                                                 const float* __restrict__ ow,
                                                 bf16* __restrict__ w1b,
                                                 bf16* __restrict__ w2b,
                                                 bf16* __restrict__ owb) {
  int i = blockIdx.x * 256 + threadIdx.x;
  const float* src; bf16* dst; int off;
  if (i < N1)           { src = w1; dst = w1b; off = i; }
  else if (i < N1 + N2) { src = w2; dst = w2b; off = i - N1; }
  else                  { src = ow; dst = owb; off = i - N1 - N2; }
  float4 v = ((const float4*)src)[off];
  bf16x4 o = {(bf16)v.x, (bf16)v.y, (bf16)v.z, (bf16)v.w};
  *(bf16x4*)(dst + 4 * (size_t)off) = o;
}

// ---------------------------------------------------------------------------
// WvT[k][j] = in_weight[(j*3+2)*768 + k], LDS-tiled 64x64 (coalesced both ways)
__global__ __launch_bounds__(256) void wvt_kernel(const float* __restrict__ in_weight,
                                                  bf16* __restrict__ wvt) {
  __shared__ float t[64][65];
  const int k0 = blockIdx.x * 64, j0 = blockIdx.y * 64;
  const int tx = threadIdx.x & 63, ty = threadIdx.x >> 6;
  for (int jj = ty; jj < 64; jj += 4)
    t[jj][tx] = in_weight[((size_t)(j0 + jj) * 3 + 2) * 768 + k0 + tx];
  __syncthreads();
  for (int kk = ty; kk < 64; kk += 4)
    wvt[(size_t)(k0 + kk) * 768 + j0 + tx] = (bf16)t[tx][kk];
}

// ---------------------------------------------------------------------------
__global__ __launch_bounds__(64) void bias_combine_kernel(const float* __restrict__ out_w,
                                                          const float* __restrict__ in_bias,
                                                          const float* __restrict__ out_b,
                                                          float* __restrict__ bc) {
  int n = blockIdx.x, l = threadIdx.x;
  float s = 0.f;
  for (int j = l; j < 768; j += 64) s += out_w[(size_t)n * 768 + j] * in_bias[j * 3 + 2];
#pragma unroll
  for (int off = 32; off > 0; off >>= 1) s += __shfl_xor(s, off, 64);
  if (l == 0) bc[n] = s + out_b[n];
}

// ---------------------------------------------------------------------------
// LayerNorm: one row (768) per 256-thread block. TIN = float or bf16.
template <typename TIN>
__global__ __launch_bounds__(256) void ln_kernel(const TIN* __restrict__ x,
                                                 const float* __restrict__ g,
                                                 const float* __restrict__ b,
                                                 bf16* __restrict__ y) {
  const int row = blockIdx.x;
  const TIN* xr = x + (size_t)row * 768;
  float v[3], s1 = 0.f, s2 = 0.f;
#pragma unroll
  for (int i = 0; i < 3; ++i) {
    v[i] = (float)xr[threadIdx.x + i * 256];
    s1 += v[i];
    s2 += v[i] * v[i];
  }
#pragma unroll
  for (int off = 32; off > 0; off >>= 1) {
    s1 += __shfl_xor(s1, off, 64);
    s2 += __shfl_xor(s2, off, 64);
  }
  __shared__ float red[8];
  int w = threadIdx.x >> 6, l = threadIdx.x & 63;
  if (l == 0) { red[w * 2] = s1; red[w * 2 + 1] = s2; }
  __syncthreads();
  s1 = red[0] + red[2] + red[4] + red[6];
  s2 = red[1] + red[3] + red[5] + red[7];
  const float mu = s1 * (1.f / 768.f);
  const float var = s2 * (1.f / 768.f) - mu * mu;
  const float rstd = rsqrtf(var + 1e-5f);
#pragma unroll
  for (int i = 0; i < 3; ++i) {
    int d = threadIdx.x + i * 256;
    y[(size_t)row * 768 + d] = (bf16)((v[i] - mu) * rstd * g[d] + b[d]);
  }
}

// ---------------------------------------------------------------------------
// C[M][N] = A[M][K] @ B[N][K]^T (+ epilogue). Block tile 128x256, BK=32,
// 512 threads = 8 waves in 2x4 (wave tile 64x64). 4-stage LDS ring (96 KB),
// prefetch distance 3, fine-grained vmcnt. Requires K/32 % 4 == 0 (24, 96 ok).
// EPI 0: bf16=acc | EPI 1: f32=acc+bias+resid | EPI 2: bf16=selu(acc+bias)
// EPI 3: bf16=acc+bias+resid
#define SLOT_E (384 * 32)   // (128 A-rows + 256 B-rows) * 32 k
template <int EPI>
__global__ __launch_bounds__(512, 2) void gemm_bt(const bf16* __restrict__ A,
                                                  const bf16* __restrict__ B,
                                                  const float* __restrict__ bias,
                                                  const bf16* __restrict__ resid,
                                                  void* __restrict__ out,
                                                  int M, int N, int K) {
  __shared__ bf16 ring[4 * SLOT_E];   // 96 KB
  const int tid = threadIdx.x;
  const int w = tid >> 6, l = tid & 63;
  const int wr = w >> 2, wcn = w & 3;       // 2x4 wave grid
  const int q = l >> 4, m16 = l & 15;

  // XCD-aware remap (XCD = linear%8): each XCD owns a contiguous band of
  // gridy/8 m-strips, m fastest -> A band L2-resident across n-tiles.
  int mtile, ntile;
  {
    const int L = blockIdx.y * gridDim.x + blockIdx.x;
    const int gy = gridDim.y;
    if ((gy & 7) == 0) {
      const int mpx = gy >> 3;
      const int xcd = L & 7;
      const int slot = L >> 3;
      mtile = xcd * mpx + (slot % mpx);
      ntile = slot / mpx;
    } else {
      mtile = blockIdx.y; ntile = blockIdx.x;
    }
  }
  const long tileM = (long)mtile * 128;
  const long tileN = (long)ntile * 256;

  // staging geometry (chunk swizzle: stored col (ch&3) holds logical col
  // ((ch&3)-(row>>1))&3 -> frag ds_read_b128 conflict-free).
  // A: 512 chunks = 1/thread; B: 1024 chunks = 2/thread.
  const int rowA = tid >> 2;
  const int clA = ((tid & 3) - (rowA >> 1)) & 3;
  const bf16* gA = A + (tileM + rowA) * (long)K + clA * 8;
  const int ldA = tid * 8;
  const bf16* gB[2]; int ldB[2];
#pragma unroll
  for (int j = 0; j < 2; ++j) {
    const int ch = tid + j * 512;
    const int row = ch >> 2;
    const int cl = ((ch & 3) - (row >> 1)) & 3;
    gB[j] = B + (tileN + row) * (long)K + cl * 8;
    ldB[j] = ch * 8;
  }

  // fragment LDS offsets (logical (r,q) lives at r*32 + ((q+(r>>1))&3)*8)
  int offA[4], offB[4];
#pragma unroll
  for (int mi = 0; mi < 4; ++mi) {
    const int r = wr * 64 + mi * 16 + m16;
    offA[mi] = r * 32 + (((q + (r >> 1)) & 3) << 3);
  }
#pragma unroll
  for (int ni = 0; ni < 4; ++ni) {
    const int r = wcn * 64 + ni * 16 + m16;
    offB[ni] = r * 32 + (((q + (r >> 1)) & 3) << 3);
  }

  f32x4 acc[4][4] = {};

  // prologue: stages 0..2 (3 loads/thread each)
#pragma unroll
  for (int s = 0; s < 3; ++s) {
    bf16* da = ring + s * SLOT_E;
    bf16* db = da + 128 * 32;
    __builtin_amdgcn_global_load_lds(AS1(gA + s * 32), AS3(&da[ldA]), 16, 0, 0);
#pragma unroll
    for (int j = 0; j < 2; ++j)
      __builtin_amdgcn_global_load_lds(AS1(gB[j] + s * 32), AS3(&db[ldB[j]]), 16, 0, 0);
  }
  long k_next = 96;

  // one K-step: wait(stage SLOT landed) -> barrier -> issue stage SLOT+3 ->
  // compute stage SLOT (16 MFMA, 8 ds_read_b128)
#define KSTEP(SLOT, WIMM, ISSUE)                                               \
  {                                                                            \
    __builtin_amdgcn_s_waitcnt(WIMM);                                          \
    __builtin_amdgcn_s_barrier();                                              \
    if (ISSUE) {                                                               \
      bf16* da = ring + (((SLOT) + 3) & 3) * SLOT_E;                           \
      bf16* db = da + 128 * 32;                                                \
      __builtin_amdgcn_global_load_lds(AS1(gA + k_next), AS3(&da[ldA]), 16, 0, 0); \
      _Pragma("unroll")                                                        \
      for (int j = 0; j < 2; ++j)                                              \
        __builtin_amdgcn_global_load_lds(AS1(gB[j] + k_next), AS3(&db[ldB[j]]), 16, 0, 0); \
      k_next += 32;                                                            \
    }                                                                          \
    const bf16* ca = ring + (SLOT) * SLOT_E;                                   \
    const bf16* cb = ca + 128 * 32;                                            \
    bf16x8 bfr[4];                                                             \
    _Pragma("unroll")                                                          \
    for (int ni = 0; ni < 4; ++ni) bfr[ni] = *(const bf16x8*)&cb[offB[ni]];    \
    _Pragma("unroll")                                                          \
    for (int mi = 0; mi < 4; ++mi) {                                           \
      const bf16x8 af = *(const bf16x8*)&ca[offA[mi]];                         \
      _Pragma("unroll")                                                        \
      for (int ni = 0; ni < 4; ++ni)                                           \
        acc[mi][ni] = __builtin_amdgcn_mfma_f32_16x16x32_bf16(af, bfr[ni],     \
                                                              acc[mi][ni], 0, 0, 0); \
    }                                                                          \
  }

  const int T = K >> 5;   // caller guarantees T % 4 == 0, T >= 8
#pragma unroll 1
  for (int g = 0; g < T - 4; g += 4) {
    KSTEP(0, VM6, 1) KSTEP(1, VM6, 1) KSTEP(2, VM6, 1) KSTEP(3, VM6, 1)
  }
  KSTEP(0, VM6, 1) KSTEP(1, VM6, 0) KSTEP(2, VM3, 0) KSTEP(3, VM0, 0)
#undef KSTEP

  // epilogue: C/D layout col = lane&15, row = (lane>>4)*4 + reg (m89-verified)
  const long colBase = tileN + (long)wcn * 64 + m16;
  const long rowBase = tileM + (long)wr * 64 + q * 4;
#pragma unroll
  for (int mi = 0; mi < 4; ++mi) {
#pragma unroll
    for (int r = 0; r < 4; ++r) {
      const long row = rowBase + mi * 16 + r;
#pragma unroll
      for (int ni = 0; ni < 4; ++ni) {
        const long col = colBase + ni * 16;
        float v = acc[mi][ni][r];
        if (EPI == 0) {
          ((bf16*)out)[row * N + col] = (bf16)v;
        } else if (EPI == 1) {
          v += bias[col] + (float)resid[row * N + col];
          ((float*)out)[row * N + col] = v;
        } else if (EPI == 2) {
          v += bias[col];
          v = v > 0.f ? 1.0507009873554805f * v
                      : 1.0507009873554805f * 1.6732632423543772f * (__expf(v) - 1.f);
          ((bf16*)out)[row * N + col] = (bf16)v;
        } else {  // EPI == 3: bf16 = acc + bias + resid
          v += bias[col] + (float)resid[row * N + col];
          ((bf16*)out)[row * N + col] = (bf16)v;
        }
      }
    }
  }
}

// ---------------------------------------------------------------------------
extern "C" void kernel_launch(void* const* d_in, const int* in_sizes, int n_in,
                              void* d_out, int out_size, void* d_ws, size_t ws_size,
                              hipStream_t stream) {
  const float* patches   = (const float*)d_in[0];
  const float* in_weight = (const float*)d_in[1];
  const float* in_bias   = (const float*)d_in[2];
  const float* out_w     = (const float*)d_in[3];
  const float* out_b     = (const float*)d_in[4];
  const float* mlp_w1    = (const float*)d_in[5];
  const float* mlp_b1    = (const float*)d_in[6];
  const float* mlp_w2    = (const float*)d_in[7];
  const float* mlp_b2    = (const float*)d_in[8];
  const float* ln1_g     = (const float*)d_in[9];
  const float* ln1_b     = (const float*)d_in[10];
  const float* ln2_g     = (const float*)d_in[11];
  const float* ln2_b     = (const float*)d_in[12];

  char* ws = (char*)d_ws;
  const size_t MB = 1024 * 1024;
  bf16* Wc   = (bf16*)(ws + 0);        // [768][768] combined proj weight
  bf16* w1b  = (bf16*)(ws + 2 * MB);
  bf16* w2b  = (bf16*)(ws + 8 * MB);
  bf16* owb  = (bf16*)(ws + 14 * MB);
  bf16* wvt  = (bf16*)(ws + 16 * MB);
  float* bc  = (float*)(ws + 18 * MB);
  bf16* X1   = (bf16*)(ws + 20 * MB);  // 25 MB; reused as X3 after proj
  bf16* X3   = (bf16*)(ws + 20 * MB);
  bf16* X2b  = (bf16*)(ws + 48 * MB);  // 25 MB; dead before H written
  bf16* H    = (bf16*)(ws + 48 * MB);  // 100 MB (aliases X2b - safe, see order)

  prep_cast<<<(N1 + N2 + N3) / 256, 256, 0, stream>>>(mlp_w1, mlp_w2, out_w,
                                                      w1b, w2b, owb);
  wvt_kernel<<<dim3(12, 12), 256, 0, stream>>>(in_weight, wvt);
  bias_combine_kernel<<<768, 64, 0, stream>>>(out_w, in_bias, out_b, bc);
  // Wc[n][k] = sum_j out_w[n][j] * WvT[k][j]
  gemm_bt<0><<<dim3(3, 6), 512, 0, stream>>>(owb, wvt, nullptr, nullptr, Wc, 768, 768, 768);

  ln_kernel<float><<<N_ROWS, 256, 0, stream>>>(patches, ln1_g, ln1_b, X1);
  // x2 = x1 @ Wc^T + bc + x1  (bf16)
  gemm_bt<3><<<dim3(3, 128), 512, 0, stream>>>(X1, Wc, bc, X1, X2b, N_ROWS, 768, 768);
  ln_kernel<bf16><<<N_ROWS, 256, 0, stream>>>(X2b, ln2_g, ln2_b, X3);
  // h = selu(x3 @ w1^T + b1)   (overwrites X2b region - X2b is dead)
  gemm_bt<2><<<dim3(12, 128), 512, 0, stream>>>(X3, w1b, mlp_b1, nullptr, H, N_ROWS, 3072, 768);
  // out = h @ w2^T + b2 + x3   (fp32 final)
  gemm_bt<1><<<dim3(3, 128), 512, 0, stream>>>(H, w2b, mlp_b2, X3, d_out, N_ROWS, 768, 3072);
}